// Round 8
// baseline (313.714 us; speedup 1.0000x reference)
//
#include <hip/hip_runtime.h>
#include <hip/hip_cooperative_groups.h>
#include <math.h>

namespace cg = cooperative_groups;

#define B 8
#define C 4
#define H 512
#define W 512
#define SEL 1
#define BIGI 1024       // H + W
#define NPIX (B*H*W)
#define CH 64           // rows per chunk
#define RC 8            // chunks per column
#define TC 32           // columns per block-unit
#define NSEG 16         // segments per chunk
#define LL 4            // rows per thread (CH/NSEG)
#define CINF 3000       // "infinite" carry
#define G 4             // rows per row unit
#define NBLK 512        // cooperative grid (2 blocks/CU on 256 CUs)
#define NCU 1024        // col units (B*16*RC)
#define NRU 1024        // row units (B*H/G)

// LDS plan: one 16640 B buffer reused across phases.
// col phase: 4 int arrays [NSEG][TC+1] at offsets 0/2112/4224/6336 (8448 B).
// row phase: float2 s2[G][W] at 0 (16384 B) + float sw[4][8] at 16384 (128 B).

__global__ __launch_bounds__(512, 4) void fused_all(const float* __restrict__ ypred,
                                                    const float* __restrict__ ytrue,
                                                    unsigned short* __restrict__ gpk,
                                                    unsigned* __restrict__ sumsD,
                                                    unsigned* __restrict__ sumsU,
                                                    float* __restrict__ rowpart,
                                                    float* __restrict__ out) {
    __shared__ __align__(16) char smem[16640];
    __shared__ double sacc[8];
    cg::grid_group grid = cg::this_grid();

    int tid = threadIdx.x;

    // ================= phase 1: vertical EDT (2 col units per block) =================
    {
        int (*sP)[TC + 1]  = (int(*)[TC + 1])(smem);
        int (*sN)[TC + 1]  = (int(*)[TC + 1])(smem + 2112);
        int (*sCP)[TC + 1] = (int(*)[TC + 1])(smem + 4224);
        int (*sCN)[TC + 1] = (int(*)[TC + 1])(smem + 6336);
        int tx  = tid & (TC - 1);
        int ty  = tid >> 5;                // 0..15
        int col = tid >> 4;                // transposed view
        int seg = tid & 15;

        for (int u = blockIdx.x; u < NCU; u += NBLK) {
            __syncthreads();               // LDS reuse across units
            int b = u >> 7, rem = u & 127, jt = rem >> 3, rc = rem & 7;
            int j = jt * TC + tx;
            int i0 = rc * CH + ty * LL;

            const float* m = ytrue + ((size_t)b * C + SEL) * H * W + j;
            int gfp[LL], gfn[LL];
            int pp = BIGI, pn = BIGI;
            #pragma unroll
            for (int r = 0; r < LL; ++r) { // local forward scan, both polarities
                bool fg = (m[(size_t)(i0 + r) * W] != 0.0f);
                int vp = fg ? BIGI : 0;
                int vn = fg ? 0 : BIGI;
                vp = min(vp, pp + 1); gfp[r] = vp; pp = vp;
                vn = min(vn, pn + 1); gfn[r] = vn; pn = vn;
            }
            sP[ty][tx] = pp - ty * LL;     // prefix-min operand
            sN[ty][tx] = pn - ty * LL;
            __syncthreads();

            int wp = sP[seg][col], wn = sN[seg][col];
            #pragma unroll
            for (int d = 1; d < NSEG; d <<= 1) {   // prefix-min over segments
                int a1 = __shfl_up(wp, d, 16);
                int a2 = __shfl_up(wn, d, 16);
                if (seg >= d) { wp = min(wp, a1); wn = min(wn, a2); }
            }
            if (seg < NSEG - 1) {
                sCP[seg + 1][col] = seg * LL + wp;
                sCN[seg + 1][col] = seg * LL + wn;
            } else {
                int jj = jt * TC + col;
                sumsD[((size_t)(b * RC + rc)) * W + jj] =
                    (unsigned)(seg * LL + wp) | ((unsigned)(seg * LL + wn) << 16);
            }
            if (seg == 0) { sCP[0][col] = BIGI; sCN[0][col] = BIGI; }
            __syncthreads();

            int cp = sCP[ty][tx], cn = sCN[ty][tx];
            int lbp = 1 << 20, lbn = 1 << 20;
            #pragma unroll
            for (int r = 0; r < LL; ++r) { // forward fix + local backward summary
                int vp = min(gfp[r], cp + 1 + r); gfp[r] = vp; lbp = min(lbp, vp + r);
                int vn = min(gfn[r], cn + 1 + r); gfn[r] = vn; lbn = min(lbn, vn + r);
            }
            sP[ty][tx] = lbp + ty * LL;    // suffix-min operand
            sN[ty][tx] = lbn + ty * LL;
            __syncthreads();

            int w2p = sP[seg][col], w2n = sN[seg][col];
            #pragma unroll
            for (int d = 1; d < NSEG; d <<= 1) {   // suffix-min over segments
                int a1 = __shfl_down(w2p, d, 16);
                int a2 = __shfl_down(w2n, d, 16);
                if (seg + d < NSEG) { w2p = min(w2p, a1); w2n = min(w2n, a2); }
            }
            if (seg > 0) {
                sCP[seg - 1][col] = w2p - seg * LL;
                sCN[seg - 1][col] = w2n - seg * LL;
            } else {
                int jj = jt * TC + col;
                sumsU[((size_t)(b * RC + rc)) * W + jj] =
                    (unsigned)w2p | ((unsigned)w2n << 16);
            }
            if (seg == NSEG - 1) { sCP[NSEG - 1][col] = BIGI; sCN[NSEG - 1][col] = BIGI; }
            __syncthreads();

            int pbp = sCP[ty][tx], pbn = sCN[ty][tx];
            unsigned short* op = gpk + ((size_t)b * H + i0) * W + j;
            #pragma unroll
            for (int r = LL - 1; r >= 0; --r) { // local backward pass + u16 packed store
                int vp = min(gfp[r], pbp + 1); pbp = vp;
                int vn = min(gfn[r], pbn + 1); pbn = vn;
                int fg = (vn == 0) ? 1 : 0;    // exactly one of vp,vn is 0
                int g2 = vp + vn;              // the nonzero one
                op[(size_t)r * W] = (unsigned short)((g2 << 1) | fg);
            }
        }
    }
    __threadfence();
    grid.sync();

    // ================= phase 2: row EDT + boundary + sigmoid + partials =================
    {
        float2 (*s2)[W] = (float2(*)[W])(smem);
        float (*sw)[8] = (float(*)[8])(smem + 16384);
        int j = tid;

        for (int u = blockIdx.x; u < NRU; u += NBLK) {
            __syncthreads();               // LDS reuse across units
            int b = u >> 7;
            int g = u & 127;
            int i0 = g * G;
            int rc = i0 >> 6;              // chunk of these G rows (CH=64)

            int Ap = CINF, An = CINF, Bp = CINF, Bn = CINF;
            #pragma unroll
            for (int q = 0; q < RC; ++q) { // inter-chunk carries (uniform branches)
                if (q < rc) {
                    unsigned dv = sumsD[((size_t)(b * RC + q)) * W + j];
                    int e = q * CH + CH - 1;
                    Ap = min(Ap, (int)(dv & 0xFFFFu) - e);
                    An = min(An, (int)(dv >> 16) - e);
                } else if (q > rc) {
                    unsigned uv = sumsU[((size_t)(b * RC + q)) * W + j];
                    int s0 = q * CH;
                    Bp = min(Bp, (int)(uv & 0xFFFFu) + s0);
                    Bn = min(Bn, (int)(uv >> 16) + s0);
                }
            }

            #pragma unroll
            for (int r = 0; r < G; ++r) {
                int ii = i0 + r;
                unsigned v = gpk[((size_t)b * H + ii) * W + j];
                int fg = v & 1;
                int gv = v >> 1;
                int gp = fg ? gv : 0;
                int gn = fg ? 0 : gv;
                gp = min(gp, min(Ap + ii, Bp - ii));   // cross-chunk fix (exact)
                gn = min(gn, min(An + ii, Bn - ii));
                s2[r][j] = make_float2((float)(gp * gp), (float)(gn * gn));
            }
            __syncthreads();

            float mxp = 0.f, mxn = 0.f, A = 0.f, Bv = 0.f;
            #pragma unroll
            for (int r = 0; r < G; ++r) {
                float2 v0 = s2[r][j];
                float bp = v0.x, bn = v0.y;
                for (int rr = 1; rr < W; ++rr) {      // exact outward scan
                    float r2 = (float)(rr * rr);
                    if (r2 >= bp && r2 >= bn) break;
                    int jl = j - rr, jr = j + rr;
                    if (jl >= 0) { float2 uu = s2[r][jl]; bp = fminf(bp, uu.x + r2); bn = fminf(bn, uu.y + r2); }
                    if (jr < W)  { float2 uu = s2[r][jr]; bp = fminf(bp, uu.x + r2); bn = fminf(bn, uu.y + r2); }
                }
                float posdis = sqrtf(bp);
                float negdis = sqrtf(bn);
                bool bnd = (bp == 1.0f);              // inner 4-boundary <=> d2pos == 1

                const float* yp = ypred + ((size_t)b * C * H + i0 + r) * W + j;
                float s = 0.f;
                #pragma unroll
                for (int cc = 0; cc < C; ++cc) {
                    float x = yp[(size_t)cc * H * W];
                    s += 1.0f / (1.0f + __expf(-x));
                }
                float se = bnd ? 0.f : s;
                mxp = fmaxf(mxp, bp); mxn = fmaxf(mxn, bn);
                A += se * posdis; Bv += se * negdis;
            }

            for (int off = 32; off >= 1; off >>= 1) {
                mxp = fmaxf(mxp, __shfl_down(mxp, off));
                mxn = fmaxf(mxn, __shfl_down(mxn, off));
                A  += __shfl_down(A, off);
                Bv += __shfl_down(Bv, off);
            }
            int wave = tid >> 6, lane = tid & 63;
            if (lane == 0) { sw[0][wave] = mxp; sw[1][wave] = mxn; sw[2][wave] = A; sw[3][wave] = Bv; }
            __syncthreads();
            if (tid == 0) {
                float a0 = sw[0][0], a1 = sw[1][0], a2 = sw[2][0], a3 = sw[3][0];
                #pragma unroll
                for (int w = 1; w < 8; ++w) {
                    a0 = fmaxf(a0, sw[0][w]); a1 = fmaxf(a1, sw[1][w]);
                    a2 += sw[2][w]; a3 += sw[3][w];
                }
                *(float4*)(rowpart + (size_t)u * 4) = make_float4(a0, a1, a2, a3);
            }
        }
    }
    __threadfence();
    grid.sync();

    // ================= phase 3: per-batch stats + total (block 0) =================
    if (blockIdx.x == 0) {
        int bw = tid >> 6;                 // wave = batch
        int lane = tid & 63;
        const float4* rv = (const float4*)(rowpart + (size_t)bw * 128 * 4);
        float4 e0 = rv[lane];
        float4 e1 = rv[lane + 64];
        float mxp = fmaxf(e0.x, e1.x), mxn = fmaxf(e0.y, e1.y);
        float A = e0.z + e1.z, Bv = e0.w + e1.w;
        for (int off = 32; off >= 1; off >>= 1) {
            mxp = fmaxf(mxp, __shfl_down(mxp, off));
            mxn = fmaxf(mxn, __shfl_down(mxn, off));
            A  += __shfl_down(A, off);
            Bv += __shfl_down(Bv, off);
        }
        if (lane == 0) {
            float pmax = sqrtf(mxp), nmax = sqrtf(mxn);
            float invp = (pmax > 0.f) ? 1.0f / pmax : 0.0f;
            float invn = (nmax > 0.f) ? 1.0f / nmax : 0.0f;
            sacc[bw] = (pmax > 0.f) ? (double)(invn * Bv - invp * A) : 0.0;
        }
        __syncthreads();
        if (tid == 0) {
            double tt = 0.0;
            #pragma unroll
            for (int q = 0; q < 8; ++q) tt += sacc[q];
            out[0] = (float)(tt / (double)((size_t)B * C * H * W));
        }
    }
}

extern "C" void kernel_launch(void* const* d_in, const int* in_sizes, int n_in,
                              void* d_out, int out_size, void* d_ws, size_t ws_size,
                              hipStream_t stream) {
    const float* ypred = (const float*)d_in[0];
    const float* ytrue = (const float*)d_in[1];
    float* out = (float*)d_out;

    unsigned short* gpk = (unsigned short*)d_ws;            // NPIX u16 ((g<<1)|fg) = 4 MB
    unsigned* sumsD = (unsigned*)(gpk + NPIX);              // B*RC*W u32 = 128 KB
    unsigned* sumsU = sumsD + (size_t)B * RC * W;           // B*RC*W u32 = 128 KB
    float* rowpart = (float*)(sumsU + (size_t)B * RC * W);  // NRU*4 f32 = 16 KB

    void* args[] = { (void*)&ypred, (void*)&ytrue, (void*)&gpk, (void*)&sumsD,
                     (void*)&sumsU, (void*)&rowpart, (void*)&out };
    hipLaunchCooperativeKernel((void*)fused_all, dim3(NBLK), dim3(512), args, 0, stream);
}

// Round 9
// 51.440 us; speedup vs baseline: 6.0987x; 6.0987x over previous
//
#include <hip/hip_runtime.h>
#include <math.h>

#define B 8
#define C 4
#define H 512
#define W 512
#define SEL 1
#define BIGI 1024       // H + W
#define NPIX (B*H*W)
#define CH 64           // rows per chunk
#define RC 8            // chunks per column
#define TC 32           // columns per block
#define NSEG 16         // segments per chunk
#define LL 4            // rows per thread (CH/NSEG)
#define CINF 3000       // "infinite" carry
#define G 4             // rows per row_fused block
#define NRU (B*H/G)     // 1024 row blocks

// ---------------- local (per-chunk) vertical EDT, both polarities, u16 packed out ----------------
__global__ __launch_bounds__(512) void col_two_level(const float* __restrict__ ytrue,
                                                     unsigned short* __restrict__ gpk,
                                                     unsigned* __restrict__ sumsD,
                                                     unsigned* __restrict__ sumsU,
                                                     unsigned* __restrict__ cnt) {
    __shared__ int sP[NSEG][TC + 1], sN[NSEG][TC + 1];
    __shared__ int sCP[NSEG][TC + 1], sCN[NSEG][TC + 1];

    if (blockIdx.x == 0 && threadIdx.x == 0) *cnt = 0u;   // re-armed every launch (replay-safe)

    int blk = blockIdx.x;              // B * 16 tiles * RC = 1024
    int b   = blk >> 7;
    int rem = blk & 127;
    int jt  = rem >> 3;
    int rc  = rem & 7;
    int tid = threadIdx.x;
    int tx  = tid & (TC - 1);
    int ty  = tid >> 5;                // 0..15
    int j   = jt * TC + tx;
    int i0  = rc * CH + ty * LL;

    const float* m = ytrue + ((size_t)b * C + SEL) * H * W + j;
    int gfp[LL], gfn[LL];
    int pp = BIGI, pn = BIGI;
    #pragma unroll
    for (int r = 0; r < LL; ++r) {     // local forward scan, both polarities
        bool fg = (m[(size_t)(i0 + r) * W] != 0.0f);
        int vp = fg ? BIGI : 0;
        int vn = fg ? 0 : BIGI;
        vp = min(vp, pp + 1); gfp[r] = vp; pp = vp;
        vn = min(vn, pn + 1); gfn[r] = vn; pn = vn;
    }
    sP[ty][tx] = pp - ty * LL;         // prefix-min operand
    sN[ty][tx] = pn - ty * LL;
    __syncthreads();

    int col = tid >> 4, seg = tid & 15;    // transposed view: 32 cols x 16 segs
    int wp = sP[seg][col], wn = sN[seg][col];
    #pragma unroll
    for (int d = 1; d < NSEG; d <<= 1) {   // prefix-min over segments
        int a1 = __shfl_up(wp, d, 16);
        int a2 = __shfl_up(wn, d, 16);
        if (seg >= d) { wp = min(wp, a1); wn = min(wn, a2); }
    }
    if (seg < NSEG - 1) {
        sCP[seg + 1][col] = seg * LL + wp;
        sCN[seg + 1][col] = seg * LL + wn;
    } else {
        int jj = jt * TC + col;
        sumsD[((size_t)(b * RC + rc)) * W + jj] =
            (unsigned)(seg * LL + wp) | ((unsigned)(seg * LL + wn) << 16);
    }
    if (seg == 0) { sCP[0][col] = BIGI; sCN[0][col] = BIGI; }
    __syncthreads();

    int cp = sCP[ty][tx], cn = sCN[ty][tx];
    int lbp = 1 << 20, lbn = 1 << 20;
    #pragma unroll
    for (int r = 0; r < LL; ++r) {     // forward fix + local backward summary
        int vp = min(gfp[r], cp + 1 + r); gfp[r] = vp; lbp = min(lbp, vp + r);
        int vn = min(gfn[r], cn + 1 + r); gfn[r] = vn; lbn = min(lbn, vn + r);
    }
    sP[ty][tx] = lbp + ty * LL;        // suffix-min operand
    sN[ty][tx] = lbn + ty * LL;
    __syncthreads();

    int w2p = sP[seg][col], w2n = sN[seg][col];
    #pragma unroll
    for (int d = 1; d < NSEG; d <<= 1) {   // suffix-min over segments
        int a1 = __shfl_down(w2p, d, 16);
        int a2 = __shfl_down(w2n, d, 16);
        if (seg + d < NSEG) { w2p = min(w2p, a1); w2n = min(w2n, a2); }
    }
    if (seg > 0) {
        sCP[seg - 1][col] = w2p - seg * LL;
        sCN[seg - 1][col] = w2n - seg * LL;
    } else {
        int jj = jt * TC + col;
        sumsU[((size_t)(b * RC + rc)) * W + jj] =
            (unsigned)w2p | ((unsigned)w2n << 16);
    }
    if (seg == NSEG - 1) { sCP[NSEG - 1][col] = BIGI; sCN[NSEG - 1][col] = BIGI; }
    __syncthreads();

    int pbp = sCP[ty][tx], pbn = sCN[ty][tx];
    unsigned short* op = gpk + ((size_t)b * H + i0) * W + j;
    #pragma unroll
    for (int r = LL - 1; r >= 0; --r) { // local backward pass + u16 packed store
        int vp = min(gfp[r], pbp + 1); pbp = vp;
        int vn = min(gfn[r], pbn + 1); pbn = vn;
        int fg = (vn == 0) ? 1 : 0;    // exactly one of vp,vn is 0
        int g2 = vp + vn;              // the nonzero one
        op[(size_t)r * W] = (unsigned short)((g2 << 1) | fg);
    }
}

// ---------------- fused row EDT (4 px/thread) + boundary + sigmoid + partials + last-block finale --
// thread t: row r=t>>7 of the G-row group, pixels j0=(t&127)*4 .. +3
__global__ __launch_bounds__(512, 4) void row_fused(const unsigned short* __restrict__ gpk,
                                                    const unsigned* __restrict__ sumsD,
                                                    const unsigned* __restrict__ sumsU,
                                                    const float* __restrict__ ypred,
                                                    float* __restrict__ rowpart,
                                                    unsigned* __restrict__ cnt,
                                                    float* __restrict__ out) {
    __shared__ float2 s2[G][W];
    __shared__ float sw[4][8];
    __shared__ int lastFlag;
    __shared__ double sacc[8];

    int blk = blockIdx.x;                 // NRU = 1024
    int b = blk >> 7;
    int g = blk & 127;
    int i0 = g * G;
    int rc = i0 >> 6;                     // chunk of these G rows (CH=64)
    int tid = threadIdx.x;
    int r = tid >> 7;                     // 0..3
    int q = tid & 127;
    int j0 = q * 4;
    int ii = i0 + r;

    // inter-chunk carries for 4 adjacent pixels (uniform branches; L2-resident)
    int Ap0 = CINF, Ap1 = CINF, Ap2 = CINF, Ap3 = CINF;
    int An0 = CINF, An1 = CINF, An2 = CINF, An3 = CINF;
    int Bp0 = CINF, Bp1 = CINF, Bp2 = CINF, Bp3 = CINF;
    int Bn0 = CINF, Bn1 = CINF, Bn2 = CINF, Bn3 = CINF;
    #pragma unroll
    for (int qq = 0; qq < RC; ++qq) {
        if (qq < rc) {
            uint4 dv = *(const uint4*)(sumsD + ((size_t)(b * RC + qq)) * W + j0);
            int e = qq * CH + CH - 1;
            Ap0 = min(Ap0, (int)(dv.x & 0xFFFFu) - e); An0 = min(An0, (int)(dv.x >> 16) - e);
            Ap1 = min(Ap1, (int)(dv.y & 0xFFFFu) - e); An1 = min(An1, (int)(dv.y >> 16) - e);
            Ap2 = min(Ap2, (int)(dv.z & 0xFFFFu) - e); An2 = min(An2, (int)(dv.z >> 16) - e);
            Ap3 = min(Ap3, (int)(dv.w & 0xFFFFu) - e); An3 = min(An3, (int)(dv.w >> 16) - e);
        } else if (qq > rc) {
            uint4 uv = *(const uint4*)(sumsU + ((size_t)(b * RC + qq)) * W + j0);
            int s0 = qq * CH;
            Bp0 = min(Bp0, (int)(uv.x & 0xFFFFu) + s0); Bn0 = min(Bn0, (int)(uv.x >> 16) + s0);
            Bp1 = min(Bp1, (int)(uv.y & 0xFFFFu) + s0); Bn1 = min(Bn1, (int)(uv.y >> 16) + s0);
            Bp2 = min(Bp2, (int)(uv.z & 0xFFFFu) + s0); Bn2 = min(Bn2, (int)(uv.z >> 16) + s0);
            Bp3 = min(Bp3, (int)(uv.w & 0xFFFFu) + s0); Bn3 = min(Bn3, (int)(uv.w >> 16) + s0);
        }
    }

    ushort4 gv4 = *(const ushort4*)(gpk + ((size_t)b * H + ii) * W + j0);
    #define FIXPX(U, GV, AP, AN, BP, BN)                                          \
        {                                                                         \
            int fg = (int)(GV) & 1;                                               \
            int gv = (int)(GV) >> 1;                                              \
            int gp = fg ? gv : 0;                                                 \
            int gn = fg ? 0 : gv;                                                 \
            gp = min(gp, min((AP) + ii, (BP) - ii));                              \
            gn = min(gn, min((AN) + ii, (BN) - ii));                              \
            s2[r][j0 + U] = make_float2((float)(gp * gp), (float)(gn * gn));      \
        }
    FIXPX(0, gv4.x, Ap0, An0, Bp0, Bn0)
    FIXPX(1, gv4.y, Ap1, An1, Bp1, Bn1)
    FIXPX(2, gv4.z, Ap2, An2, Bp2, Bn2)
    FIXPX(3, gv4.w, Ap3, An3, Bp3, Bn3)
    #undef FIXPX
    __syncthreads();

    // vectorized ypred read: 4 channels x 4 adjacent pixels
    const float* yp = ypred + ((size_t)b * C * H + ii) * W + j0;
    float4 y0 = *(const float4*)(yp);
    float4 y1 = *(const float4*)(yp + (size_t)H * W);
    float4 y2 = *(const float4*)(yp + (size_t)2 * H * W);
    float4 y3 = *(const float4*)(yp + (size_t)3 * H * W);

    float mxp = 0.f, mxn = 0.f, A = 0.f, Bv = 0.f;
    #pragma unroll
    for (int u = 0; u < 4; ++u) {
        int j = j0 + u;
        float2 v0 = s2[r][j];
        float bp = v0.x, bn = v0.y;
        for (int rr = 1; rr < W; ++rr) {      // exact outward scan, both polarities
            float r2 = (float)(rr * rr);
            if (r2 >= bp && r2 >= bn) break;  // unvisited candidates >= r2 -> exact
            int jl = j - rr, jr = j + rr;
            if (jl >= 0) { float2 uu = s2[r][jl]; bp = fminf(bp, uu.x + r2); bn = fminf(bn, uu.y + r2); }
            if (jr < W)  { float2 uu = s2[r][jr]; bp = fminf(bp, uu.x + r2); bn = fminf(bn, uu.y + r2); }
        }
        float posdis = sqrtf(bp);
        float negdis = sqrtf(bn);
        bool bnd = (bp == 1.0f);              // inner 4-boundary <=> d2pos == 1

        float x0 = (u == 0) ? y0.x : (u == 1) ? y0.y : (u == 2) ? y0.z : y0.w;
        float x1 = (u == 0) ? y1.x : (u == 1) ? y1.y : (u == 2) ? y1.z : y1.w;
        float x2 = (u == 0) ? y2.x : (u == 1) ? y2.y : (u == 2) ? y2.z : y2.w;
        float x3 = (u == 0) ? y3.x : (u == 1) ? y3.y : (u == 2) ? y3.z : y3.w;
        float s = 1.0f / (1.0f + __expf(-x0)) + 1.0f / (1.0f + __expf(-x1))
                + 1.0f / (1.0f + __expf(-x2)) + 1.0f / (1.0f + __expf(-x3));
        float se = bnd ? 0.f : s;
        mxp = fmaxf(mxp, bp); mxn = fmaxf(mxn, bn);
        A += se * posdis; Bv += se * negdis;
    }

    for (int off = 32; off >= 1; off >>= 1) {
        mxp = fmaxf(mxp, __shfl_down(mxp, off));
        mxn = fmaxf(mxn, __shfl_down(mxn, off));
        A  += __shfl_down(A, off);
        Bv += __shfl_down(Bv, off);
    }
    int wave = tid >> 6, lane = tid & 63;
    if (lane == 0) { sw[0][wave] = mxp; sw[1][wave] = mxn; sw[2][wave] = A; sw[3][wave] = Bv; }
    __syncthreads();
    if (tid == 0) {
        float a0 = sw[0][0], a1 = sw[1][0], a2 = sw[2][0], a3 = sw[3][0];
        #pragma unroll
        for (int w = 1; w < 8; ++w) {
            a0 = fmaxf(a0, sw[0][w]); a1 = fmaxf(a1, sw[1][w]);
            a2 += sw[2][w]; a3 += sw[3][w];
        }
        *(float4*)(rowpart + (size_t)blk * 4) = make_float4(a0, a1, a2, a3);
        __threadfence();
        unsigned prev = atomicAdd(cnt, 1u);
        lastFlag = (prev == (unsigned)(NRU - 1)) ? 1 : 0;
    }
    __syncthreads();

    // ---------------- last block: per-batch stats + total (deterministic) ----------------
    if (lastFlag) {
        __threadfence();                      // acquire: see all rowpart writes
        int bw = tid >> 6;                    // wave = batch
        const float4* rv = (const float4*)(rowpart + (size_t)bw * 128 * 4);
        float4 e0 = rv[lane];
        float4 e1 = rv[lane + 64];
        float fmxp = fmaxf(e0.x, e1.x), fmxn = fmaxf(e0.y, e1.y);
        float fA = e0.z + e1.z, fBv = e0.w + e1.w;
        for (int off = 32; off >= 1; off >>= 1) {
            fmxp = fmaxf(fmxp, __shfl_down(fmxp, off));
            fmxn = fmaxf(fmxn, __shfl_down(fmxn, off));
            fA  += __shfl_down(fA, off);
            fBv += __shfl_down(fBv, off);
        }
        if (lane == 0) {
            float pmax = sqrtf(fmxp), nmax = sqrtf(fmxn);
            float invp = (pmax > 0.f) ? 1.0f / pmax : 0.0f;
            float invn = (nmax > 0.f) ? 1.0f / nmax : 0.0f;
            sacc[bw] = (pmax > 0.f) ? (double)(invn * fBv - invp * fA) : 0.0;
        }
        __syncthreads();
        if (tid == 0) {
            double tt = 0.0;
            #pragma unroll
            for (int qb = 0; qb < 8; ++qb) tt += sacc[qb];
            out[0] = (float)(tt / (double)((size_t)B * C * H * W));
        }
    }
}

extern "C" void kernel_launch(void* const* d_in, const int* in_sizes, int n_in,
                              void* d_out, int out_size, void* d_ws, size_t ws_size,
                              hipStream_t stream) {
    const float* ypred = (const float*)d_in[0];
    const float* ytrue = (const float*)d_in[1];
    float* out = (float*)d_out;

    unsigned short* gpk = (unsigned short*)d_ws;            // NPIX u16 ((g<<1)|fg) = 4 MB
    unsigned* sumsD = (unsigned*)(gpk + NPIX);              // B*RC*W u32 = 128 KB
    unsigned* sumsU = sumsD + (size_t)B * RC * W;           // B*RC*W u32 = 128 KB
    float* rowpart = (float*)(sumsU + (size_t)B * RC * W);  // NRU*4 f32 = 16 KB
    unsigned* cnt = (unsigned*)(rowpart + (size_t)NRU * 4); // 1 u32 (zeroed by col kernel)

    col_two_level<<<B * 16 * RC, 512, 0, stream>>>(ytrue, gpk, sumsD, sumsU, cnt);
    row_fused<<<NRU, 512, 0, stream>>>(gpk, sumsD, sumsU, ypred, rowpart, cnt, out);
}

// Round 10
// 46.842 us; speedup vs baseline: 6.6972x; 1.0981x over previous
//
#include <hip/hip_runtime.h>
#include <math.h>

#define B 8
#define C 4
#define H 512
#define W 512
#define SEL 1
#define BIGI 1024       // H + W
#define NPIX (B*H*W)
#define CH 64           // rows per chunk
#define RC 8            // chunks per column
#define TC 32           // columns per block
#define NSEG 16         // segments per chunk
#define LL 4            // rows per thread (CH/NSEG)
#define CINF 3000       // "infinite" carry
#define G 4             // rows per row_fused block
#define NRU (B*H/G)     // 1024 row blocks

// ---------------- local (per-chunk) vertical EDT, both polarities, u16 packed out ----------------
__global__ __launch_bounds__(512) void col_two_level(const float* __restrict__ ytrue,
                                                     unsigned short* __restrict__ gpk,
                                                     unsigned* __restrict__ sumsD,
                                                     unsigned* __restrict__ sumsU,
                                                     unsigned* __restrict__ cnt) {
    __shared__ int sP[NSEG][TC + 1], sN[NSEG][TC + 1];
    __shared__ int sCP[NSEG][TC + 1], sCN[NSEG][TC + 1];

    if (blockIdx.x == 0 && threadIdx.x == 0) *cnt = 0u;   // re-armed every launch (replay-safe)

    int blk = blockIdx.x;              // B * 16 tiles * RC = 1024
    int b   = blk >> 7;
    int rem = blk & 127;
    int jt  = rem >> 3;
    int rc  = rem & 7;
    int tid = threadIdx.x;
    int tx  = tid & (TC - 1);
    int ty  = tid >> 5;                // 0..15
    int j   = jt * TC + tx;
    int i0  = rc * CH + ty * LL;

    const float* m = ytrue + ((size_t)b * C + SEL) * H * W + j;
    int gfp[LL], gfn[LL];
    int pp = BIGI, pn = BIGI;
    #pragma unroll
    for (int r = 0; r < LL; ++r) {     // local forward scan, both polarities
        bool fg = (m[(size_t)(i0 + r) * W] != 0.0f);
        int vp = fg ? BIGI : 0;
        int vn = fg ? 0 : BIGI;
        vp = min(vp, pp + 1); gfp[r] = vp; pp = vp;
        vn = min(vn, pn + 1); gfn[r] = vn; pn = vn;
    }
    sP[ty][tx] = pp - ty * LL;         // prefix-min operand
    sN[ty][tx] = pn - ty * LL;
    __syncthreads();

    int col = tid >> 4, seg = tid & 15;    // transposed view: 32 cols x 16 segs
    int wp = sP[seg][col], wn = sN[seg][col];
    #pragma unroll
    for (int d = 1; d < NSEG; d <<= 1) {   // prefix-min over segments
        int a1 = __shfl_up(wp, d, 16);
        int a2 = __shfl_up(wn, d, 16);
        if (seg >= d) { wp = min(wp, a1); wn = min(wn, a2); }
    }
    if (seg < NSEG - 1) {
        sCP[seg + 1][col] = seg * LL + wp;
        sCN[seg + 1][col] = seg * LL + wn;
    } else {
        int jj = jt * TC + col;
        sumsD[((size_t)(b * RC + rc)) * W + jj] =
            (unsigned)(seg * LL + wp) | ((unsigned)(seg * LL + wn) << 16);
    }
    if (seg == 0) { sCP[0][col] = BIGI; sCN[0][col] = BIGI; }
    __syncthreads();

    int cp = sCP[ty][tx], cn = sCN[ty][tx];
    int lbp = 1 << 20, lbn = 1 << 20;
    #pragma unroll
    for (int r = 0; r < LL; ++r) {     // forward fix + local backward summary
        int vp = min(gfp[r], cp + 1 + r); gfp[r] = vp; lbp = min(lbp, vp + r);
        int vn = min(gfn[r], cn + 1 + r); gfn[r] = vn; lbn = min(lbn, vn + r);
    }
    sP[ty][tx] = lbp + ty * LL;        // suffix-min operand
    sN[ty][tx] = lbn + ty * LL;
    __syncthreads();

    int w2p = sP[seg][col], w2n = sN[seg][col];
    #pragma unroll
    for (int d = 1; d < NSEG; d <<= 1) {   // suffix-min over segments
        int a1 = __shfl_down(w2p, d, 16);
        int a2 = __shfl_down(w2n, d, 16);
        if (seg + d < NSEG) { w2p = min(w2p, a1); w2n = min(w2n, a2); }
    }
    if (seg > 0) {
        sCP[seg - 1][col] = w2p - seg * LL;
        sCN[seg - 1][col] = w2n - seg * LL;
    } else {
        int jj = jt * TC + col;
        sumsU[((size_t)(b * RC + rc)) * W + jj] =
            (unsigned)w2p | ((unsigned)w2n << 16);
    }
    if (seg == NSEG - 1) { sCP[NSEG - 1][col] = BIGI; sCN[NSEG - 1][col] = BIGI; }
    __syncthreads();

    int pbp = sCP[ty][tx], pbn = sCN[ty][tx];
    unsigned short* op = gpk + ((size_t)b * H + i0) * W + j;
    #pragma unroll
    for (int r = LL - 1; r >= 0; --r) { // local backward pass + u16 packed store
        int vp = min(gfp[r], pbp + 1); pbp = vp;
        int vn = min(gfn[r], pbn + 1); pbn = vn;
        int fg = (vn == 0) ? 1 : 0;    // exactly one of vp,vn is 0
        int g2 = vp + vn;              // the nonzero one
        op[(size_t)r * W] = (unsigned short)((g2 << 1) | fg);
    }
}

// ---------------- fused row EDT (thread = pixel, G rows) + sigmoid + partials + finale ----------
__global__ __launch_bounds__(512, 4) void row_fused(const unsigned short* __restrict__ gpk,
                                                    const unsigned* __restrict__ sumsD,
                                                    const unsigned* __restrict__ sumsU,
                                                    const float* __restrict__ ypred,
                                                    float* __restrict__ rowpart,
                                                    unsigned* __restrict__ cnt,
                                                    float* __restrict__ out) {
    __shared__ float2 s2[G][W];
    __shared__ float sw[4][8];
    __shared__ int lastFlag;
    __shared__ double sacc[8];

    int blk = blockIdx.x;                 // NRU = 1024
    int b = blk >> 7;
    int g = blk & 127;
    int i0 = g * G;
    int rc = i0 >> 6;                     // chunk of these G rows (CH=64)
    int tid = threadIdx.x;
    int j = tid;

    // inter-chunk carries from summaries (uniform branches; L2-resident)
    int Ap = CINF, An = CINF, Bp = CINF, Bn = CINF;
    #pragma unroll
    for (int q = 0; q < RC; ++q) {
        if (q < rc) {
            unsigned dv = sumsD[((size_t)(b * RC + q)) * W + j];
            int e = q * CH + CH - 1;
            Ap = min(Ap, (int)(dv & 0xFFFFu) - e);
            An = min(An, (int)(dv >> 16) - e);
        } else if (q > rc) {
            unsigned uv = sumsU[((size_t)(b * RC + q)) * W + j];
            int s0 = q * CH;
            Bp = min(Bp, (int)(uv & 0xFFFFu) + s0);
            Bn = min(Bn, (int)(uv >> 16) + s0);
        }
    }

    #pragma unroll
    for (int r = 0; r < G; ++r) {
        int ii = i0 + r;
        unsigned v = gpk[((size_t)b * H + ii) * W + j];
        int fg = v & 1;
        int gv = v >> 1;
        int gp = fg ? gv : 0;
        int gn = fg ? 0 : gv;
        gp = min(gp, min(Ap + ii, Bp - ii));   // cross-chunk fix (exact)
        gn = min(gn, min(An + ii, Bn - ii));
        s2[r][j] = make_float2((float)(gp * gp), (float)(gn * gn));
    }
    __syncthreads();

    float mxp = 0.f, mxn = 0.f, A = 0.f, Bv = 0.f;
    #pragma unroll
    for (int r = 0; r < G; ++r) {
        float2 v0 = s2[r][j];
        float bp = v0.x, bn = v0.y;
        for (int rr = 1; rr < W; ++rr) {      // exact outward scan, both polarities
            float r2 = (float)(rr * rr);
            if (r2 >= bp && r2 >= bn) break;  // unvisited candidates >= r2 -> exact
            int jl = j - rr, jr = j + rr;
            if (jl >= 0) { float2 uu = s2[r][jl]; bp = fminf(bp, uu.x + r2); bn = fminf(bn, uu.y + r2); }
            if (jr < W)  { float2 uu = s2[r][jr]; bp = fminf(bp, uu.x + r2); bn = fminf(bn, uu.y + r2); }
        }
        float posdis = sqrtf(bp);
        float negdis = sqrtf(bn);
        bool bnd = (bp == 1.0f);              // inner 4-boundary <=> d2pos == 1

        const float* yp = ypred + ((size_t)b * C * H + i0 + r) * W + j;
        float s = 0.f;
        #pragma unroll
        for (int cc = 0; cc < C; ++cc) {
            float x = yp[(size_t)cc * H * W];
            s += 1.0f / (1.0f + __expf(-x));
        }
        float se = bnd ? 0.f : s;
        mxp = fmaxf(mxp, bp); mxn = fmaxf(mxn, bn);
        A += se * posdis; Bv += se * negdis;
    }

    for (int off = 32; off >= 1; off >>= 1) {
        mxp = fmaxf(mxp, __shfl_down(mxp, off));
        mxn = fmaxf(mxn, __shfl_down(mxn, off));
        A  += __shfl_down(A, off);
        Bv += __shfl_down(Bv, off);
    }
    int wave = tid >> 6, lane = tid & 63;
    if (lane == 0) { sw[0][wave] = mxp; sw[1][wave] = mxn; sw[2][wave] = A; sw[3][wave] = Bv; }
    __syncthreads();
    if (tid == 0) {
        float a0 = sw[0][0], a1 = sw[1][0], a2 = sw[2][0], a3 = sw[3][0];
        #pragma unroll
        for (int w = 1; w < 8; ++w) {
            a0 = fmaxf(a0, sw[0][w]); a1 = fmaxf(a1, sw[1][w]);
            a2 += sw[2][w]; a3 += sw[3][w];
        }
        *(float4*)(rowpart + (size_t)blk * 4) = make_float4(a0, a1, a2, a3);
        __threadfence();
        unsigned prev = atomicAdd(cnt, 1u);
        lastFlag = (prev == (unsigned)(NRU - 1)) ? 1 : 0;
    }
    __syncthreads();

    // ---------------- last block: per-batch stats + total (deterministic) ----------------
    if (lastFlag) {
        __threadfence();                      // acquire: see all rowpart writes
        int bw = tid >> 6;                    // wave = batch
        const float4* rv = (const float4*)(rowpart + (size_t)bw * 128 * 4);
        float4 e0 = rv[lane];
        float4 e1 = rv[lane + 64];
        float fmxp = fmaxf(e0.x, e1.x), fmxn = fmaxf(e0.y, e1.y);
        float fA = e0.z + e1.z, fBv = e0.w + e1.w;
        for (int off = 32; off >= 1; off >>= 1) {
            fmxp = fmaxf(fmxp, __shfl_down(fmxp, off));
            fmxn = fmaxf(fmxn, __shfl_down(fmxn, off));
            fA  += __shfl_down(fA, off);
            fBv += __shfl_down(fBv, off);
        }
        if (lane == 0) {
            float pmax = sqrtf(fmxp), nmax = sqrtf(fmxn);
            float invp = (pmax > 0.f) ? 1.0f / pmax : 0.0f;
            float invn = (nmax > 0.f) ? 1.0f / nmax : 0.0f;
            sacc[bw] = (pmax > 0.f) ? (double)(invn * fBv - invp * fA) : 0.0;
        }
        __syncthreads();
        if (tid == 0) {
            double tt = 0.0;
            #pragma unroll
            for (int qb = 0; qb < 8; ++qb) tt += sacc[qb];
            out[0] = (float)(tt / (double)((size_t)B * C * H * W));
        }
    }
}

extern "C" void kernel_launch(void* const* d_in, const int* in_sizes, int n_in,
                              void* d_out, int out_size, void* d_ws, size_t ws_size,
                              hipStream_t stream) {
    const float* ypred = (const float*)d_in[0];
    const float* ytrue = (const float*)d_in[1];
    float* out = (float*)d_out;

    unsigned short* gpk = (unsigned short*)d_ws;            // NPIX u16 ((g<<1)|fg) = 4 MB
    unsigned* sumsD = (unsigned*)(gpk + NPIX);              // B*RC*W u32 = 128 KB
    unsigned* sumsU = sumsD + (size_t)B * RC * W;           // B*RC*W u32 = 128 KB
    float* rowpart = (float*)(sumsU + (size_t)B * RC * W);  // NRU*4 f32 = 16 KB
    unsigned* cnt = (unsigned*)(rowpart + (size_t)NRU * 4); // 1 u32 (zeroed by col kernel)

    col_two_level<<<B * 16 * RC, 512, 0, stream>>>(ytrue, gpk, sumsD, sumsU, cnt);
    row_fused<<<NRU, 512, 0, stream>>>(gpk, sumsD, sumsU, ypred, rowpart, cnt, out);
}

// Round 11
// 25.164 us; speedup vs baseline: 12.4665x; 1.8615x over previous
//
#include <hip/hip_runtime.h>
#include <math.h>

#define B 8
#define C 4
#define H 512
#define W 512
#define SEL 1
#define BIGI 1024       // H + W
#define NPIX (B*H*W)
#define CH 64           // rows per chunk
#define RC 8            // chunks per column
#define TC 32           // columns per block
#define NSEG 16         // segments per chunk
#define LL 4            // rows per thread (CH/NSEG)
#define CINF 3000       // "infinite" carry
#define G 4             // rows per row_fused block
#define NRU (B*H/G)     // 1024 row blocks

// ---------------- local (per-chunk) vertical EDT, both polarities, u16 packed out ----------------
__global__ __launch_bounds__(512) void col_two_level(const float* __restrict__ ytrue,
                                                     unsigned short* __restrict__ gpk,
                                                     unsigned* __restrict__ sumsD,
                                                     unsigned* __restrict__ sumsU) {
    __shared__ int sP[NSEG][TC + 1], sN[NSEG][TC + 1];
    __shared__ int sCP[NSEG][TC + 1], sCN[NSEG][TC + 1];

    int blk = blockIdx.x;              // B * 16 tiles * RC = 1024
    int b   = blk >> 7;
    int rem = blk & 127;
    int jt  = rem >> 3;
    int rc  = rem & 7;
    int tid = threadIdx.x;
    int tx  = tid & (TC - 1);
    int ty  = tid >> 5;                // 0..15
    int j   = jt * TC + tx;
    int i0  = rc * CH + ty * LL;

    const float* m = ytrue + ((size_t)b * C + SEL) * H * W + j;
    int gfp[LL], gfn[LL];
    int pp = BIGI, pn = BIGI;
    #pragma unroll
    for (int r = 0; r < LL; ++r) {     // local forward scan, both polarities
        bool fg = (m[(size_t)(i0 + r) * W] != 0.0f);
        int vp = fg ? BIGI : 0;
        int vn = fg ? 0 : BIGI;
        vp = min(vp, pp + 1); gfp[r] = vp; pp = vp;
        vn = min(vn, pn + 1); gfn[r] = vn; pn = vn;
    }
    sP[ty][tx] = pp - ty * LL;         // prefix-min operand
    sN[ty][tx] = pn - ty * LL;
    __syncthreads();

    int col = tid >> 4, seg = tid & 15;    // transposed view: 32 cols x 16 segs
    int wp = sP[seg][col], wn = sN[seg][col];
    #pragma unroll
    for (int d = 1; d < NSEG; d <<= 1) {   // prefix-min over segments
        int a1 = __shfl_up(wp, d, 16);
        int a2 = __shfl_up(wn, d, 16);
        if (seg >= d) { wp = min(wp, a1); wn = min(wn, a2); }
    }
    if (seg < NSEG - 1) {
        sCP[seg + 1][col] = seg * LL + wp;
        sCN[seg + 1][col] = seg * LL + wn;
    } else {
        int jj = jt * TC + col;
        sumsD[((size_t)(b * RC + rc)) * W + jj] =
            (unsigned)(seg * LL + wp) | ((unsigned)(seg * LL + wn) << 16);
    }
    if (seg == 0) { sCP[0][col] = BIGI; sCN[0][col] = BIGI; }
    __syncthreads();

    int cp = sCP[ty][tx], cn = sCN[ty][tx];
    int lbp = 1 << 20, lbn = 1 << 20;
    #pragma unroll
    for (int r = 0; r < LL; ++r) {     // forward fix + local backward summary
        int vp = min(gfp[r], cp + 1 + r); gfp[r] = vp; lbp = min(lbp, vp + r);
        int vn = min(gfn[r], cn + 1 + r); gfn[r] = vn; lbn = min(lbn, vn + r);
    }
    sP[ty][tx] = lbp + ty * LL;        // suffix-min operand
    sN[ty][tx] = lbn + ty * LL;
    __syncthreads();

    int w2p = sP[seg][col], w2n = sN[seg][col];
    #pragma unroll
    for (int d = 1; d < NSEG; d <<= 1) {   // suffix-min over segments
        int a1 = __shfl_down(w2p, d, 16);
        int a2 = __shfl_down(w2n, d, 16);
        if (seg + d < NSEG) { w2p = min(w2p, a1); w2n = min(w2n, a2); }
    }
    if (seg > 0) {
        sCP[seg - 1][col] = w2p - seg * LL;
        sCN[seg - 1][col] = w2n - seg * LL;
    } else {
        int jj = jt * TC + col;
        sumsU[((size_t)(b * RC + rc)) * W + jj] =
            (unsigned)w2p | ((unsigned)w2n << 16);
    }
    if (seg == NSEG - 1) { sCP[NSEG - 1][col] = BIGI; sCN[NSEG - 1][col] = BIGI; }
    __syncthreads();

    int pbp = sCP[ty][tx], pbn = sCN[ty][tx];
    unsigned short* op = gpk + ((size_t)b * H + i0) * W + j;
    #pragma unroll
    for (int r = LL - 1; r >= 0; --r) { // local backward pass + u16 packed store
        int vp = min(gfp[r], pbp + 1); pbp = vp;
        int vn = min(gfn[r], pbn + 1); pbn = vn;
        int fg = (vn == 0) ? 1 : 0;    // exactly one of vp,vn is 0
        int g2 = vp + vn;              // the nonzero one
        op[(size_t)r * W] = (unsigned short)((g2 << 1) | fg);
    }
}

// ---------------- fused row EDT (sign-packed single scan) + sigmoid + partials ----------------
// invariant: per pixel exactly one of (d2pos, d2neg) is nonzero; sv = fg ? +g^2 : -g^2.
// neighbor candidate: same side -> |u| + r^2, opposite side -> r^2  ==  fmax(u*sgn,0) + r^2.
// rowpart[blk] = {mx_d2pos, mx_d2neg, sum s*posdis, sum s*negdis}
__global__ __launch_bounds__(512) void row_fused(const unsigned short* __restrict__ gpk,
                                                 const unsigned* __restrict__ sumsD,
                                                 const unsigned* __restrict__ sumsU,
                                                 const float* __restrict__ ypred,
                                                 float* __restrict__ rowpart) {
    __shared__ float s1[G][W];
    __shared__ float sw[4][8];

    int blk = blockIdx.x;                 // NRU = 1024
    int b = blk >> 7;
    int g = blk & 127;
    int i0 = g * G;
    int rc = i0 >> 6;                     // chunk of these G rows (CH=64)
    int j = threadIdx.x;

    // inter-chunk carries from summaries (uniform branches; L2-resident)
    int Ap = CINF, An = CINF, Bp = CINF, Bn = CINF;
    #pragma unroll
    for (int q = 0; q < RC; ++q) {
        if (q < rc) {
            unsigned dv = sumsD[((size_t)(b * RC + q)) * W + j];
            int e = q * CH + CH - 1;
            Ap = min(Ap, (int)(dv & 0xFFFFu) - e);
            An = min(An, (int)(dv >> 16) - e);
        } else if (q > rc) {
            unsigned uv = sumsU[((size_t)(b * RC + q)) * W + j];
            int s0 = q * CH;
            Bp = min(Bp, (int)(uv & 0xFFFFu) + s0);
            Bn = min(Bn, (int)(uv >> 16) + s0);
        }
    }

    #pragma unroll
    for (int r = 0; r < G; ++r) {
        int ii = i0 + r;
        unsigned v = gpk[((size_t)b * H + ii) * W + j];
        int fg = v & 1;
        int gv = v >> 1;
        int gp = fg ? gv : 0;
        int gn = fg ? 0 : gv;
        gp = min(gp, min(Ap + ii, Bp - ii));   // cross-chunk fix (exact, preserves invariant)
        gn = min(gn, min(An + ii, Bn - ii));
        int gg = gp + gn;                      // the nonzero one
        float sv = (float)(gg * gg);
        s1[r][j] = fg ? sv : -sv;
    }
    __syncthreads();

    float mxp = 0.f, mxn = 0.f, A = 0.f, Bv = 0.f;
    #pragma unroll
    for (int r = 0; r < G; ++r) {
        float sv = s1[r][j];
        bool fg = (sv > 0.f);
        float sgn = fg ? 1.f : -1.f;
        float bq = fabsf(sv);
        for (int rr = 1; rr < W; ++rr) {      // exact outward scan, single value
            float r2 = (float)(rr * rr);
            if (r2 >= bq) break;              // unvisited candidates >= r2 -> exact
            int jl = j - rr, jr = j + rr;
            if (jl >= 0) { float u = s1[r][jl]; bq = fminf(bq, fmaxf(u * sgn, 0.f) + r2); }
            if (jr < W)  { float u = s1[r][jr]; bq = fminf(bq, fmaxf(u * sgn, 0.f) + r2); }
        }
        float d = sqrtf(bq);
        bool bnd = fg && (bq == 1.0f);        // inner 4-boundary <=> d2pos == 1

        const float* yp = ypred + ((size_t)b * C * H + i0 + r) * W + j;
        float s = 0.f;
        #pragma unroll
        for (int cc = 0; cc < C; ++cc) {
            float x = yp[(size_t)cc * H * W];
            s += 1.0f / (1.0f + __expf(-x));
        }
        float se = bnd ? 0.f : s;
        mxp = fmaxf(mxp, fg ? bq : 0.f);
        mxn = fmaxf(mxn, fg ? 0.f : bq);
        A  += fg ? se * d : 0.f;
        Bv += fg ? 0.f : se * d;
    }

    for (int off = 32; off >= 1; off >>= 1) {
        mxp = fmaxf(mxp, __shfl_down(mxp, off));
        mxn = fmaxf(mxn, __shfl_down(mxn, off));
        A  += __shfl_down(A, off);
        Bv += __shfl_down(Bv, off);
    }
    int wave = threadIdx.x >> 6, lane = threadIdx.x & 63;
    if (lane == 0) { sw[0][wave] = mxp; sw[1][wave] = mxn; sw[2][wave] = A; sw[3][wave] = Bv; }
    __syncthreads();
    if (threadIdx.x == 0) {
        float a0 = sw[0][0], a1 = sw[1][0], a2 = sw[2][0], a3 = sw[3][0];
        #pragma unroll
        for (int w = 1; w < 8; ++w) {
            a0 = fmaxf(a0, sw[0][w]); a1 = fmaxf(a1, sw[1][w]);
            a2 += sw[2][w]; a3 += sw[3][w];
        }
        *(float4*)(rowpart + (size_t)blk * 4) = make_float4(a0, a1, a2, a3);
    }
}

// ---------------- per-batch stats + total: one wave per batch ----------------
__global__ __launch_bounds__(512) void batch_final(const float* __restrict__ rowpart,
                                                   float* __restrict__ out) {
    __shared__ double sacc[8];
    int bw = threadIdx.x >> 6;            // wave = batch
    int lane = threadIdx.x & 63;
    const float4* rv = (const float4*)(rowpart + (size_t)bw * 128 * 4);
    float4 e0 = rv[lane];
    float4 e1 = rv[lane + 64];
    float mxp = fmaxf(e0.x, e1.x), mxn = fmaxf(e0.y, e1.y);
    float A = e0.z + e1.z, Bv = e0.w + e1.w;
    for (int off = 32; off >= 1; off >>= 1) {
        mxp = fmaxf(mxp, __shfl_down(mxp, off));
        mxn = fmaxf(mxn, __shfl_down(mxn, off));
        A  += __shfl_down(A, off);
        Bv += __shfl_down(Bv, off);
    }
    if (lane == 0) {
        float pmax = sqrtf(mxp), nmax = sqrtf(mxn);
        float invp = (pmax > 0.f) ? 1.0f / pmax : 0.0f;
        float invn = (nmax > 0.f) ? 1.0f / nmax : 0.0f;
        sacc[bw] = (pmax > 0.f) ? (double)(invn * Bv - invp * A) : 0.0;
    }
    __syncthreads();
    if (threadIdx.x == 0) {
        double tt = 0.0;
        #pragma unroll
        for (int q = 0; q < 8; ++q) tt += sacc[q];
        out[0] = (float)(tt / (double)((size_t)B * C * H * W));
    }
}

extern "C" void kernel_launch(void* const* d_in, const int* in_sizes, int n_in,
                              void* d_out, int out_size, void* d_ws, size_t ws_size,
                              hipStream_t stream) {
    const float* ypred = (const float*)d_in[0];
    const float* ytrue = (const float*)d_in[1];
    float* out = (float*)d_out;

    unsigned short* gpk = (unsigned short*)d_ws;            // NPIX u16 ((g<<1)|fg) = 4 MB
    unsigned* sumsD = (unsigned*)(gpk + NPIX);              // B*RC*W u32 = 128 KB
    unsigned* sumsU = sumsD + (size_t)B * RC * W;           // B*RC*W u32 = 128 KB
    float* rowpart = (float*)(sumsU + (size_t)B * RC * W);  // NRU*4 f32 = 16 KB

    col_two_level<<<B * 16 * RC, 512, 0, stream>>>(ytrue, gpk, sumsD, sumsU);
    row_fused<<<NRU, 512, 0, stream>>>(gpk, sumsD, sumsU, ypred, rowpart);
    batch_final<<<1, 512, 0, stream>>>(rowpart, out);
}